// Round 4
// baseline (213.088 us; speedup 1.0000x reference)
//
#include <hip/hip_runtime.h>

#define HH 448
#define WW 608
#define CC 64
#define S1 32
#define S2 16
#define HW (HH * WW)
#define BLK 640
#define NCH 4096   // float4 chunks per 32-channel half: 32 classes * 32 ch * 16 k2 / 4

typedef __attribute__((address_space(1))) const void* gp1_t;
typedef __attribute__((address_space(3))) void* lp3_t;

// LDS layout (per 32-channel half, 64KB):
//   element (k, cl, k2) at word  k*512 + (cl ^ ((k>>2)&1))*16 + 4*((k2>>2) ^ (k&3)) + (k2&3)
// Staged via global_load_lds(16B): LDS dest is linear in chunk index i (wave-uniform
// base + lane*16 within each wave-slice), the permutation is applied to the per-lane
// GLOBAL source address (m173 pattern). Verified bijective: for fixed k, XOR by
// constants in clx and q2x.
__device__ __forceinline__ void stage_chunk(const float* __restrict__ w2row,
                                            float* w2s_base, int i, int hf) {
    const int k   = i >> 7;          // class 0..31
    const int r   = i & 127;
    const int clx = r >> 2;          // swizzled channel-in-half
    const int q2x = r & 3;           // swizzled k2-quad
    const int cl  = clx ^ ((k >> 2) & 1);
    const int c   = hf * 32 + cl;
    const int k2q = q2x ^ (k & 3);
    const int g   = ((k << 6) + c) * 4 + k2q;   // float4 index in w2 row
    __builtin_amdgcn_global_load_lds((gp1_t)(w2row + (size_t)g * 4),
                                     (lp3_t)(w2s_base + (size_t)i * 4),
                                     16, 0, 0);
}

__launch_bounds__(BLK, 5)
__global__ void reg2stage_kernel(const float* __restrict__ x,
                                 const float* __restrict__ w1,
                                 const float* __restrict__ b1,
                                 const float* __restrict__ w2,
                                 const float* __restrict__ b2,
                                 const float* __restrict__ w3,
                                 const float* __restrict__ b3,
                                 float* __restrict__ out) {
    __shared__ float w2s[S1 * 32 * S2];   // 64 KB (one c-half)
    __shared__ float b2s[S1 * S2];        // 2 KB

    const int h = blockIdx.x;
    const int tid = threadIdx.x;
    const bool active = (tid < WW);
    const int w = tid;

    const float* __restrict__ w2row = w2 + (size_t)h * (S1 * CC * S2);

    // ---- issue half-0 staging (direct-to-LDS, latency hides under stage 1) ----
#pragma unroll
    for (int j = 0; j < 6; ++j) stage_chunk(w2row, w2s, tid + j * BLK, 0);
    if (tid < NCH - 6 * BLK) stage_chunk(w2row, w2s, 6 * BLK + tid, 0);  // 256-chunk tail

    float b2v = 0.0f;
    if (tid < S1 * S2) b2v = b2[(size_t)h * (S1 * S2) + tid];   // tid = k*16 + k2

    // ---- pixel channel vector ----
    float xv[CC];
    if (active) {
        const float* __restrict__ xp = x + (size_t)h * WW + w;
#pragma unroll
        for (int c = 0; c < CC; ++c) xv[c] = xp[(size_t)c * HW];
    }

    // ---- stage 1: per-row GEMV + argmax ----
    // NOTE: single sequential FMA chain per class, verbatim from rounds 1/2.
    // This summation order empirically produces ZERO argmax flips vs the np
    // reference (2 passing runs); the round-3 4-chain split flipped near-ties
    // (absmax 17 = k1 flip). Do not "optimize" this ordering.
    const float* __restrict__ w1r = w1 + (size_t)h * (S1 * CC);
    const float* __restrict__ b1r = b1 + (size_t)h * S1;
    float best1 = -INFINITY;
    int k1 = 0;
    if (active) {
        for (int k = 0; k < S1; ++k) {
            float acc = b1r[k];
            const float* __restrict__ wk = w1r + k * CC;
#pragma unroll
            for (int c = 0; c < CC; ++c) acc += xv[c] * wk[c];
            if (acc > best1) { best1 = acc; k1 = k; }
        }
    }

    if (tid < S1 * S2) {
        const int k = tid >> 4, k2 = tid & 15;
        b2s[k2 * 32 + k] = b2v;               // read lanes vary k -> conflict-free
    }
    __syncthreads();   // drains vmcnt -> half-0 resident

    // ---- stage 2: per-channel scalar ascending (round-1-proven ordering) ----
    float acc2[S2];
    const int kbase = k1 << 9;                // k1*512
    const int clxor = (k1 >> 2) & 1;
    const int q2xor = k1 & 3;
    if (active) {
#pragma unroll
        for (int t = 0; t < S2; ++t) acc2[t] = b2s[t * 32 + k1];
#pragma unroll 8
        for (int cl = 0; cl < 32; ++cl) {     // c-half 0: channels 0..31
            const float xc = xv[cl];
            const int rowb = kbase + ((cl ^ clxor) << 4);
#pragma unroll
            for (int q = 0; q < 4; ++q) {
                const float4 v = *reinterpret_cast<const float4*>(
                    &w2s[rowb + ((q ^ q2xor) << 2)]);
                acc2[4 * q + 0] += xc * v.x;
                acc2[4 * q + 1] += xc * v.y;
                acc2[4 * q + 2] += xc * v.z;
                acc2[4 * q + 3] += xc * v.w;
            }
        }
    }
    __syncthreads();   // everyone done reading half-0

    // ---- issue half-1 staging ----
#pragma unroll
    for (int j = 0; j < 6; ++j) stage_chunk(w2row, w2s, tid + j * BLK, 1);
    if (tid < NCH - 6 * BLK) stage_chunk(w2row, w2s, 6 * BLK + tid, 1);
    __syncthreads();   // drains vmcnt -> half-1 resident

    if (!active) return;

#pragma unroll 8
    for (int cl = 0; cl < 32; ++cl) {         // c-half 1: channels 32..63
        const float xc = xv[32 + cl];
        const int rowb = kbase + ((cl ^ clxor) << 4);
#pragma unroll
        for (int q = 0; q < 4; ++q) {
            const float4 v = *reinterpret_cast<const float4*>(
                &w2s[rowb + ((q ^ q2xor) << 2)]);
            acc2[4 * q + 0] += xc * v.x;
            acc2[4 * q + 1] += xc * v.y;
            acc2[4 * q + 2] += xc * v.z;
            acc2[4 * q + 3] += xc * v.w;
        }
    }

    float best2 = -INFINITY;
    int k2b = 0;
#pragma unroll
    for (int k2 = 0; k2 < S2; ++k2) {
        if (acc2[k2] > best2) { best2 = acc2[k2]; k2b = k2; }
    }

    // ---- stage 3: per-pixel (C x 2) matvec gathered from global (L2/L3 resident) ----
    const size_t ind2 = ((size_t)h * S1 + k1) * S2 + k2b;
    const float4* __restrict__ w3p =
        reinterpret_cast<const float4*>(w3 + ind2 * (CC * 2));
    float r0 = b3[ind2 * 2];
    float r1 = b3[ind2 * 2 + 1];
#pragma unroll
    for (int j = 0; j < 32; ++j) {
        const float4 q = w3p[j];              // channels 2j, 2j+1
        r0 += xv[2 * j] * q.x + xv[2 * j + 1] * q.z;
        r1 += xv[2 * j] * q.y + xv[2 * j + 1] * q.w;
    }

    const int loc = k1 * S2 + k2b;            // inds2 - h*S1*S2
    const float x_out = ((float)loc + r0) * 0.5f;
    const float mask = (r1 >= 0.0f) ? r1 : 0.01f * r1;

    out[(size_t)h * WW + w] = x_out;
    out[(size_t)HW + (size_t)h * WW + w] = mask;
}

extern "C" void kernel_launch(void* const* d_in, const int* in_sizes, int n_in,
                              void* d_out, int out_size, void* d_ws, size_t ws_size,
                              hipStream_t stream) {
    const float* x  = (const float*)d_in[0];
    const float* w1 = (const float*)d_in[1];
    const float* b1 = (const float*)d_in[2];
    const float* w2 = (const float*)d_in[3];
    const float* b2 = (const float*)d_in[4];
    const float* w3 = (const float*)d_in[5];
    const float* b3 = (const float*)d_in[6];
    float* out = (float*)d_out;

    reg2stage_kernel<<<dim3(HH), dim3(BLK), 0, stream>>>(x, w1, b1, w2, b2, w3, b3, out);
}